// Round 16
// baseline (619.132 us; speedup 1.0000x reference)
//
#include <hip/hip_runtime.h>

typedef unsigned short u16;
typedef signed char s8;
typedef __attribute__((ext_vector_type(4))) float f32x4;
typedef __attribute__((ext_vector_type(4))) int i32x4;

#define M_ROWS 8192
#define N_OUT  14336
#define K_IN   4096
#define NTILE  64   // K_IN / 64

__constant__ float NF4_TAB[16] = {
    -1.0f, -0.6961928009986877f, -0.5250730514526367f, -0.39491748809814453f,
    -0.28444138169288635f, -0.18477343022823334f, -0.09105003625154495f, 0.0f,
    0.07958029955625534f, 0.16093020141124725f, 0.24611230194568634f,
    0.33791524171829224f, 0.44070982933044434f, 0.5626170039176941f,
    0.7229568362236023f, 1.0f};

static __device__ __forceinline__ void async_load16(const void* g, void* l) {
  __builtin_amdgcn_global_load_lds(
      (const __attribute__((address_space(1))) void*)g,
      (__attribute__((address_space(3))) void*)l, 16, 0, 0);
}

// ---------------------------------------------------------------------------
// W -> i8 with PER-COLUMN scale (verified R14): one block per output column.
// ---------------------------------------------------------------------------
__global__ __launch_bounds__(256) void quant_w_kernel(
    const int* __restrict__ wp, const float* __restrict__ wa,
    s8* __restrict__ wout, float* __restrict__ sn) {
  const int n = blockIdx.x;
  const int t = threadIdx.x, lane = t & 63, wid = t >> 6;
  const i32x4 p0 = __builtin_nontemporal_load(
      reinterpret_cast<const i32x4*>(wp) + (size_t)n * 512 + 2 * t);
  const i32x4 p1 = __builtin_nontemporal_load(
      reinterpret_cast<const i32x4*>(wp) + (size_t)n * 512 + 2 * t + 1);
  const float am = wa[n * 64 + (t >> 2)];

  float v[16];
  int pv[8] = {p0.x, p0.y, p0.z, p0.w, p1.x, p1.y, p1.z, p1.w};
  float mx = 0.0f;
#pragma unroll
  for (int i = 0; i < 8; ++i) {
    v[2 * i]     = NF4_TAB[(pv[i] >> 4) & 15];
    v[2 * i + 1] = NF4_TAB[pv[i] & 15];
  }
#pragma unroll
  for (int i = 0; i < 16; ++i) mx = fmaxf(mx, fabsf(v[i]));
  mx *= am;
#pragma unroll
  for (int off = 32; off; off >>= 1) mx = fmaxf(mx, __shfl_xor(mx, off));
  __shared__ float red[4];
  if (lane == 0) red[wid] = mx;
  __syncthreads();
  const float colmax = fmaxf(fmaxf(red[0], red[1]), fmaxf(red[2], red[3]));
  const float inv = colmax > 0.0f ? (127.0f * am) / colmax : 0.0f;

  union { s8 c[16]; i32x4 q; } o;
#pragma unroll
  for (int i = 0; i < 16; ++i) o.c[i] = (s8)(int)rintf(v[i] * inv);
  reinterpret_cast<i32x4*>(wout)[(size_t)n * 256 + t] = o.q;
  if (t == 0) sn[n] = colmax * (1.0f / 127.0f);
}

// ---------------------------------------------------------------------------
// X -> i8 with per-row scale (verified R13/R14): one block per row.
// ---------------------------------------------------------------------------
__global__ __launch_bounds__(256) void quant_x_kernel(
    const float* __restrict__ x, s8* __restrict__ xi8,
    float* __restrict__ sxr) {
  const int row = blockIdx.x;
  const int tid = threadIdx.x, lane = tid & 63, wid = tid >> 6;
  const float4* xr = reinterpret_cast<const float4*>(x + (size_t)row * 4096);
  float4 v[4];
  float mx = 0.0f;
#pragma unroll
  for (int i = 0; i < 4; ++i) {
    v[i] = xr[tid * 4 + i];
    mx = fmaxf(mx, fmaxf(fmaxf(fabsf(v[i].x), fabsf(v[i].y)),
                         fmaxf(fabsf(v[i].z), fabsf(v[i].w))));
  }
#pragma unroll
  for (int off = 32; off; off >>= 1) mx = fmaxf(mx, __shfl_xor(mx, off));
  __shared__ float red[4];
  if (lane == 0) red[wid] = mx;
  __syncthreads();
  mx = fmaxf(fmaxf(red[0], red[1]), fmaxf(red[2], red[3]));
  float rs = mx > 0.0f ? 127.0f / mx : 0.0f;
  union { s8 c[16]; i32x4 q; } o;
#pragma unroll
  for (int i = 0; i < 4; ++i) {
    o.c[4 * i + 0] = (s8)(int)rintf(v[i].x * rs);
    o.c[4 * i + 1] = (s8)(int)rintf(v[i].y * rs);
    o.c[4 * i + 2] = (s8)(int)rintf(v[i].z * rs);
    o.c[4 * i + 3] = (s8)(int)rintf(v[i].w * rs);
  }
  reinterpret_cast<i32x4*>(xi8 + (size_t)row * 4096)[tid] = o.q;
  if (tid == 0) sxr[row] = mx * (1.0f / 127.0f);
}

// ---------------------------------------------------------------------------
// 256x128 INT8 GEMM, mfma_i32_16x16x64_i8, DEPTH-3 pipeline with counted
// vmcnt (T4): body s reads buf[s%3], stages tile s+2 into buf[(s+2)%3], ends
// with vmcnt(3) = "tile s+1's 3 per-wave loads landed, s+2's in flight" --
// stage latency gets a FULL TILE of slack, never drains to 0 in the loop
// (R15's per-tile VM(0) drain removed). 2 blocks/CU retained (LDS 72 KB x 2
// = 144 <= 160; launch_bounds(512,4)) for cross-block pipe overlap.
// Per wave 64x64: acc[4][4] i32x4 (AGPR via MFMA C chain), pure-i32 exact
// accumulation; scales sn[col]*sxr[row] in epilogue (R14, absmax 1.30).
// Swizzle verified 0-conflict (R14/R15). Race audit: tiles s,s+1,s+2 occupy
// distinct bufs mod 3; buf[(s+2)%3]'s reads completed before the barrier
// ending body s-1; all waves issue exactly 3 gloads/stage so vmcnt(3) is
// exact per wave. Tail: bodies 62/63 skip staging; VM(0) at 62.
// ---------------------------------------------------------------------------
__global__ __launch_bounds__(512, 4) void gemm_nf4_i8(
    const s8* __restrict__ A,    // [M][K] i8
    const s8* __restrict__ B,    // [N][K] i8
    float* __restrict__ C, const int* __restrict__ bp,
    const float* __restrict__ ba, const float* __restrict__ sn,
    const float* __restrict__ sxr) {
  constexpr int K = K_IN, N = N_OUT;
  extern __shared__ char smem[];
  char* sA = smem;                          // [3][256][64] i8 = 48 KB
  char* sB = smem + 49152;                  // [3][128][64] i8 = 24 KB

  const int tid = threadIdx.x;
  const int w = tid >> 6, lane = tid & 63;
  const int r = lane & 15, kq = lane >> 4;
  const int wr = w >> 1, wc = w & 1;        // 4 x 2 wave grid, 64x64 each

  // bijective XCD swizzle (3584 % 8 == 0) + mt-inner-8 supertile
  int bid = blockIdx.x;
  int cpx = gridDim.x >> 3;                 // 448
  int wg = (bid & 7) * cpx + (bid >> 3);
  int grp = wg / 896;                       // 896 = 112 nt * 8 mt
  int rem = wg - grp * 896;
  int nt = rem >> 3;                        // 0..111
  int mt = grp * 8 + (rem & 7);             // 0..31
  const size_t m0 = (size_t)mt * 256, n0 = (size_t)nt * 128;

  const s8* gA = A + m0 * K;
  const s8* gB = B + n0 * K;

  // read-side swizzled chunk offset (bytes); row bases all multiples of 16
  const int cswz = ((kq ^ ((r >> 1) & 3)) << 4);
  // stage-side global chunk (involution partner, R14-verified)
  const int cg16 = (((lane & 3) ^ ((lane >> 3) & 3)) << 4);
  const int rl = lane >> 2;

  // hoisted stage source pointers (advance by s*64 bytes per K-tile)
  const s8* stA0 = gA + (size_t)(w * 16 + rl) * K + cg16;
  const s8* stA1 = gA + (size_t)(128 + w * 16 + rl) * K + cg16;
  const s8* stB0 = gB + (size_t)(w * 16 + rl) * K + cg16;

  i32x4 acc[4][4] = {};        // 64 regs -> AGPRs via MFMA C chain
  i32x4 aF[4];

#define BAR() __builtin_amdgcn_s_barrier()
#define VM(n) asm volatile("s_waitcnt vmcnt(" #n ")" ::: "memory")

  // exactly 3 gload_lds per wave per stage -> vmcnt counts are exact
#define STAGE_AB(P, s) do {                                                   \
    async_load16(stA0 + (size_t)(s) * 64, sA + (P) * 16384 + w * 1024);       \
    async_load16(stA1 + (size_t)(s) * 64, sA + (P) * 16384 + 8192 + w * 1024);\
    async_load16(stB0 + (size_t)(s) * 64, sB + (P) * 8192 + w * 1024);        \
  } while (0)

#define READ_A(P) do {                                                       \
    const char* pa_ = sA + (P) * 16384 + (wr * 64 + r) * 64;                 \
    _Pragma("unroll")                                                        \
    for (int m_ = 0; m_ < 4; ++m_)                                           \
      aF[m_] = *(const i32x4*)(pa_ + m_ * 1024 + cswz);                      \
  } while (0)

  // stream one B fragment at a time (4 live VGPRs), 4 MFMA per fragment
#define MFMA_ALL(P) do {                                                     \
    const char* pb_ = sB + (P) * 8192 + (wc * 64 + r) * 64;                  \
    __builtin_amdgcn_s_setprio(1);                                           \
    _Pragma("unroll")                                                        \
    for (int n_ = 0; n_ < 4; ++n_) {                                         \
      i32x4 bF_ = *(const i32x4*)(pb_ + n_ * 1024 + cswz);                   \
      _Pragma("unroll")                                                      \
      for (int m_ = 0; m_ < 4; ++m_)                                         \
        acc[m_][n_] = __builtin_amdgcn_mfma_i32_16x16x64_i8(                 \
            aF[m_], bF_, acc[m_][n_], 0, 0, 0);                              \
    }                                                                        \
    __builtin_amdgcn_s_setprio(0);                                           \
  } while (0)

  // BODY(tile s, read buf P, stage buf PS): stage tile s+2 into PS
#define BODY(s, P, PS, DO_STAGE, DO_SYNC, VMSTMT) do {                       \
    READ_A(P);                                                               \
    if (DO_STAGE) STAGE_AB(PS, (s) + 2);                                     \
    MFMA_ALL(P);                                                             \
    if (DO_SYNC) { VMSTMT; BAR(); }                                          \
  } while (0)

  // prologue: stage tiles 0,1 into bufs 0,1; wait tile 0 only (vmcnt(3))
  STAGE_AB(0, 0); STAGE_AB(1, 1);
  VM(3); BAR();

  for (int s = 0; s < 60; s += 3) {
    BODY(s,     0, 2, 1, 1, VM(3));
    BODY(s + 1, 1, 0, 1, 1, VM(3));
    BODY(s + 2, 2, 1, 1, 1, VM(3));
  }
  BODY(60, 0, 2, 1, 1, VM(3));   // stages tile 62 -> buf 2
  BODY(61, 1, 0, 1, 1, VM(3));   // stages tile 63 -> buf 0
  BODY(62, 2, 0, 0, 1, VM(0));   // no stage; full drain (tile 63 landed)
  BODY(63, 0, 0, 0, 0, (void)0); // tail: no stage, no sync

  // epilogue: out = (float)acc * sn[col] * sxr[row] + bias[col]
  // C/D layout (16x16): col = lane&15, row = kq*4 + j  (R14-verified)
  float bias[4], snv[4];
#pragma unroll
  for (int ni = 0; ni < 4; ++ni) {
    int col = (int)n0 + wc * 64 + ni * 16 + r;
    int byte = bp[col >> 1];
    int code = (col & 1) ? (byte & 15) : ((byte >> 4) & 15);
    bias[ni] = NF4_TAB[code] * ba[col >> 6];
    snv[ni] = sn[col];
  }
#pragma unroll
  for (int mi = 0; mi < 4; ++mi) {
    size_t row0 = m0 + wr * 64 + mi * 16 + kq * 4;
    const f32x4 sxv = *reinterpret_cast<const f32x4*>(sxr + row0);
#pragma unroll
    for (int ni = 0; ni < 4; ++ni) {
      size_t col = n0 + wc * 64 + ni * 16 + r;
#pragma unroll
      for (int j = 0; j < 4; ++j)
        C[(row0 + j) * N + col] =
            (float)acc[mi][ni][j] * (snv[ni] * sxv[j]) + bias[ni];
    }
  }
#undef BODY
#undef MFMA_ALL
#undef READ_A
#undef STAGE_AB
#undef VM
#undef BAR
}

extern "C" void kernel_launch(void* const* d_in, const int* in_sizes, int n_in,
                              void* d_out, int out_size, void* d_ws,
                              size_t ws_size, hipStream_t stream) {
  const float* x  = (const float*)d_in[0];
  const int* wp   = (const int*)d_in[1];
  const float* wa = (const float*)d_in[2];
  const int* bp   = (const int*)d_in[3];
  const float* ba = (const float*)d_in[4];
  float* out = (float*)d_out;

  // workspace layout
  s8* Wi8 = (s8*)d_ws;                                   //  58,720,256 B
  s8* Xi8 = Wi8 + (size_t)N_OUT * K_IN;                  //  33,554,432 B
  float* sn  = (float*)(Xi8 + (size_t)M_ROWS * K_IN);    //      57,344 B
  float* sxr = sn + N_OUT;                               //      32,768 B

  quant_w_kernel<<<N_OUT, 256, 0, stream>>>(wp, wa, Wi8, sn);
  quant_x_kernel<<<M_ROWS, 256, 0, stream>>>(x, Xi8, sxr);

  hipFuncSetAttribute(reinterpret_cast<const void*>(gemm_nf4_i8),
                      hipFuncAttributeMaxDynamicSharedMemorySize, 73728);
  // 32 m-tiles x 112 n-tiles
  gemm_nf4_i8<<<3584, 512, 73728, stream>>>(Xi8, Wi8, out, bp, ba, sn, sxr);
}